// Round 13
// baseline (72.823 us; speedup 1.0000x reference)
//
#include <hip/hip_runtime.h>
#include <math.h>

#define L_ 8192
#define EMB_ 256
#define HID_ 64

typedef __attribute__((ext_vector_type(8))) short bf16x8;
typedef __attribute__((ext_vector_type(4))) float f32x4;
typedef __attribute__((ext_vector_type(4))) int i32x4;

// workspace layout (floats)
#define OFF_TFB  0           // ushort[512][2][64][8]  synthesis B-frags, hi only
#define OFF_TLB  262144      // ushort[256][4][64][8]  analysis B-frags, hi only
#define OFF_AFB  524288      // ushort[32][6][4][64][16] A-frags (hi+lo)
#define OFF_XFRP 917504      // float[8][128][2048] per-Kseg DFT partials, transposed
#define OFF_B2   3014656     // float[32*64]
#define OFF_PHI  3016704     // float[32*32*4]
#define OFF_GB   3020800     // float2[32*64]

__device__ inline int pkbf(float a, float b) {
    int r;
    asm volatile("v_cvt_pk_bf16_f32 %0, %1, %2" : "=v"(r) : "v"(a), "v"(b));
    return r;
}
__device__ inline bf16x8 asbf(i32x4 v) { union { i32x4 i; bf16x8 h; } u; u.i = v; return u.h; }
#define MFMA(A,B,C) __builtin_amdgcn_mfma_f32_16x16x32_bf16((A),(B),(C),0,0,0)

__device__ inline ushort f2bf(float v) {
    unsigned b = __float_as_uint(v);
    return (ushort)((b + 0x7FFFu + ((b >> 16) & 1u)) >> 16);
}
__device__ inline float bf2f(ushort h) { return __uint_as_float(((unsigned)h) << 16); }
// hardware trig: input in REVOLUTIONS (D = sin/cos(S0 * 2pi)); arg r/8192 is already reduced
__device__ inline float hwsin(float rev) { float r; asm("v_sin_f32 %0, %1" : "=v"(r) : "v"(rev)); return r; }
__device__ inline float hwcos(float rev) { float r; asm("v_cos_f32 %0, %1" : "=v"(r) : "v"(rev)); return r; }

// merged: trig tables (blocks 0..4095) + phi (4096..4111) + mlp (4112..4143)
__global__ __launch_bounds__(256) void k_init(ushort* __restrict__ TLB, ushort* __restrict__ TFB,
        const float* __restrict__ emb,
        const float* __restrict__ Arp, const float* __restrict__ Aip,
        const float* __restrict__ Arn, const float* __restrict__ Ain, float* __restrict__ phi,
        const float* __restrict__ w1, const float* __restrict__ b1,
        const float* __restrict__ w2, const float* __restrict__ b2, float* __restrict__ gb) {
    int bid = blockIdx.x;
    if (bid < 4096) {
        int idx = bid * 256 + threadIdx.x;   // 0..1048575
        int f, l; ushort* dst;
        if (idx < 524288) {                  // TLB: [kstep 256][ct 4][lane 64][e 8]
            int u = idx;
            int e = u & 7, lane = (u >> 3) & 63, ct = (u >> 9) & 3, kstep = u >> 11;
            l = kstep * 32 + ((lane >> 4) << 3) + e;
            f = ct * 16 + (lane & 15);
            dst = TLB + u;
        } else {                             // TFB: [lt 512][ts 2][lane 64][e 8]
            int u = idx - 524288;
            int e = u & 7, lane = (u >> 3) & 63, ts = (u >> 9) & 1, lt = u >> 10;
            l = lt * 16 + (lane & 15);
            f = ts * 32 + ((lane >> 4) << 3) + e;
            dst = TFB + u;
        }
        int fr = f & 31; bool sinp = (f & 32) != 0;
        int r = (fr * l) & (L_ - 1);
        float rev = (float)r * (1.0f / (float)L_);
        float v = sinp ? hwsin(rev) : hwcos(rev);
        *dst = f2bf(v);
    } else if (bid < 4112) {
        int tid = (bid - 4096) * 256 + threadIdx.x;   // (b*32+mm)*4+cmp
        int b = tid >> 7;
        int mm = (tid >> 2) & 31;
        int cmp = tid & 3;
        const float* A = (cmp == 0) ? Arp : (cmp == 1) ? Aip : (cmp == 2) ? Arn : Ain;
        const float4* e4 = (const float4*)(emb + b * EMB_);
        const float4* a4 = (const float4*)(A + mm * EMB_);
        float acc = 0.f;
        for (int q = 0; q < EMB_ / 4; ++q) {
            float4 ev = e4[q], av = a4[q];
            acc += ev.x * av.x + ev.y * av.y + ev.z * av.z + ev.w * av.w;
        }
        phi[tid] = acc;
    } else {
        __shared__ float h[HID_];
        int b = bid - 4112, t = threadIdx.x;
        if (t < HID_) {
            const float4* e4 = (const float4*)(emb + b * EMB_);
            const float4* w4 = (const float4*)(w1 + t * EMB_);
            float acc = b1[t];
            for (int q = 0; q < EMB_ / 4; ++q) {
                float4 ev = e4[q], wv = w4[q];
                acc += ev.x * wv.x + ev.y * wv.y + ev.z * wv.z + ev.w * wv.w;
            }
            h[t] = acc / (1.f + expf(-acc));
        }
        __syncthreads();
        if (t < 128) {
            float g = b2[t];
            const float4* h4 = (const float4*)h;
            const float4* w4 = (const float4*)(w2 + t * HID_);
            for (int q = 0; q < HID_ / 4; ++q) {
                float4 hv = h4[q], wv = w4[q];
                g += hv.x * wv.x + hv.y * wv.y + hv.z * wv.z + hv.w * wv.w;
            }
            if (t < 64) gb[(b * 64 + t) * 2 + 0] = 1.f + g;
            else        gb[(b * 64 + (t - 64)) * 2 + 1] = g;
        }
    }
}

// single-bf16 MFMA DFT; grid 1024 = stripe(128: 16 rows) x lseg(8: K=1024); 4 waves split K
// depth-3 x prefetch + 1-deep TLB prefetch; stores transposed partials xfrp[lseg][col][row]
__global__ __launch_bounds__(256) void k_dft(const float* __restrict__ x,
        const ushort* __restrict__ TLB, float* __restrict__ xfrp) {
    __shared__ float sP[4][16][132];
    int stripe = blockIdx.x >> 3;
    int lseg = blockIdx.x & 7;
    int w = threadIdx.x >> 6;
    int lane = threadIdx.x & 63;
    int row = lane & 15, koff = (lane >> 4) << 3;
    int r0 = stripe * 16;
    int kb0 = lseg * 1024 + w * 256;

    f32x4 acc[8];
    #pragma unroll
    for (int i = 0; i < 8; ++i) acc[i] = (f32x4){0.f, 0.f, 0.f, 0.f};

    const float* ap = x + (size_t)(r0 + row) * L_ + kb0 + koff;
    const i32x4* tb = (const i32x4*)TLB;
    int tbase = (kb0 >> 5) * 256 + lane;    // i32x4 index; +256 per kstep, +64 per ct
    const i32x4 SM = {(int)0x80000000, (int)0x80000000, (int)0x80000000, (int)0x80000000};

    float4 xa0 = *(const float4*)(ap);
    float4 xc0 = *(const float4*)(ap + 4);
    float4 xa1 = *(const float4*)(ap + 32);
    float4 xc1 = *(const float4*)(ap + 36);
    float4 xa2 = *(const float4*)(ap + 64);
    float4 xc2 = *(const float4*)(ap + 68);
    i32x4 t0 = tb[tbase], t1 = tb[tbase + 64], t2 = tb[tbase + 128], t3 = tb[tbase + 192];
    for (int ks = 0; ks < 8; ++ks) {
        float4 nxa = {0,0,0,0}, nxc = {0,0,0,0};
        i32x4 n0 = t0, n1 = t1, n2 = t2, n3 = t3;
        if (ks < 5) {
            nxa = *(const float4*)(ap + (ks + 3) * 32);
            nxc = *(const float4*)(ap + (ks + 3) * 32 + 4);
        }
        if (ks < 7) {
            int ti = tbase + (ks + 1) * 256;
            n0 = tb[ti]; n1 = tb[ti + 64]; n2 = tb[ti + 128]; n3 = tb[ti + 192];
        }
        int h0 = pkbf(xa0.x, xa0.y), h1 = pkbf(xa0.z, xa0.w);
        int h2 = pkbf(xc0.x, xc0.y), h3 = pkbf(xc0.z, xc0.w);
        bf16x8 AH = asbf((i32x4){h0, h1, h2, h3});
        acc[0] = MFMA(AH, asbf(t0), acc[0]); acc[4] = MFMA(AH, asbf(t0 ^ SM), acc[4]);
        acc[1] = MFMA(AH, asbf(t1), acc[1]); acc[5] = MFMA(AH, asbf(t1 ^ SM), acc[5]);
        acc[2] = MFMA(AH, asbf(t2), acc[2]); acc[6] = MFMA(AH, asbf(t2 ^ SM), acc[6]);
        acc[3] = MFMA(AH, asbf(t3), acc[3]); acc[7] = MFMA(AH, asbf(t3 ^ SM), acc[7]);
        xa0 = xa1; xc0 = xc1; xa1 = xa2; xc1 = xc2; xa2 = nxa; xc2 = nxc;
        t0 = n0; t1 = n1; t2 = n2; t3 = n3;
    }
    int crow = (lane >> 4) << 2;
    int ccol = lane & 15;
    #pragma unroll
    for (int ct = 0; ct < 8; ++ct)
        #pragma unroll
        for (int r = 0; r < 4; ++r)
            sP[w][crow + r][ct * 16 + ccol] = acc[ct][r];
    __syncthreads();
    #pragma unroll
    for (int i = 0; i < 8; ++i) {
        int e = threadIdx.x + 256 * i;     // 0..2047
        int rr = e & 15, cc = e >> 4;
        float s = sP[0][rr][cc] + sP[1][rr][cc] + sP[2][rr][cc] + sP[3][rr][cc];
        xfrp[((size_t)(lseg * 128 + cc)) * 2048 + r0 + rr] = s;
    }
}

// mode mixing -> AFB fragments directly.
// blocks 0..127: [mm 32][side 2][bh 2] spectral rows; blocks 128..159: Ax fold + bias2 per b
__global__ __launch_bounds__(256) void k_mix(const float* __restrict__ xfrt,
        const float* __restrict__ wpos, const float* __restrict__ wneg,
        const float* __restrict__ phi, const float* __restrict__ lw,
        const float* __restrict__ lb, const float* __restrict__ gb,
        ushort* __restrict__ afb, float* __restrict__ bias2) {
    int bi = blockIdx.x;
    int tid = threadIdx.x;
    if (bi >= 128) {                 // Ax fold + bias2
        int b = bi - 128;
        ushort* dst = afb + (size_t)b * 24576;
        #pragma unroll
        for (int j = 0; j < 16; ++j) {
            int u = tid + 256 * j;   // 0..4095 : [ks2 2][mt 4][lane 64][e 8]
            int e = u & 7, lane = (u >> 3) & 63, mt = (u >> 9) & 3, ks2 = u >> 11;
            int c = mt * 16 + (lane & 15);
            int kk = ((lane >> 4) << 3) + e;
            float v = lw[c * 64 + ks2 * 32 + kk] * gb[(b * 64 + c) * 2];
            ushort hi = f2bf(v);
            int base = (((4 + ks2) * 4 + mt) * 64 + lane) * 16;
            dst[base + e] = hi;
            dst[base + 8 + e] = f2bf(v - bf2f(hi));
        }
        if (tid < 64) {
            float g1 = gb[(b * 64 + tid) * 2], be = gb[(b * 64 + tid) * 2 + 1];
            bias2[b * 64 + tid] = lb[tid] * g1 + be;
        }
        return;
    }
    __shared__ float sW[64][64][2];     // [i][o][re/im]
    __shared__ float sXr[16][64], sXi[16][64];   // [b_local][i]
    int bh = bi & 1, side = (bi >> 1) & 1, mm = bi >> 2;
    int slot = side ? (31 - mm) : mm;
    int colR = side ? (64 + slot) : mm;
    int colI = side ? (96 + slot) : (32 + mm);

    const float* W = side ? wneg : wpos;
    #pragma unroll
    for (int j = 0; j < 16; ++j) {
        int fidx = tid + 256 * j;       // 0..4095 = i*64+o
        int i = fidx >> 6, o = fidx & 63;
        float2 wv = *(const float2*)&W[(size_t)(i * 64 + o) * 64 + mm * 2];
        sW[i][o][0] = wv.x;
        sW[i][o][1] = wv.y;
    }
    {
        const float4* pR = (const float4*)(xfrt + (size_t)colR * 2048 + bh * 1024);
        const float4* pI = (const float4*)(xfrt + (size_t)colI * 2048 + bh * 1024);
        float4 aR = {0, 0, 0, 0}, aI = {0, 0, 0, 0};
        #pragma unroll
        for (int s = 0; s < 8; ++s) {
            float4 vR = pR[(size_t)s * 65536 + tid];
            float4 vI = pI[(size_t)s * 65536 + tid];
            aR.x += vR.x; aR.y += vR.y; aR.z += vR.z; aR.w += vR.w;
            aI.x += vI.x; aI.y += vI.y; aI.z += vI.z; aI.w += vI.w;
        }
        if (!side) { aI.x = -aI.x; aI.y = -aI.y; aI.z = -aI.z; aI.w = -aI.w; }
        *(float4*)&sXr[tid >> 4][(tid & 15) * 4] = aR;
        *(float4*)&sXi[tid >> 4][(tid & 15) * 4] = aI;
    }
    __syncthreads();

    int o = tid & 63, bg = tid >> 6;
    const float invL = 1.f / (float)L_;
    float fac = (slot == 0) ? invL : 2.f * invL;
    int comp = side ? 2 : 0;
    int e = slot & 7, kgrp = slot >> 3;
    int mt = o >> 4, lane = kgrp * 16 + (o & 15);
    #pragma unroll
    for (int bl = 0; bl < 4; ++bl) {
        int b_local = bg * 4 + bl;
        int b = bh * 16 + b_local;
        float sre = 0.f, sim = 0.f;
        #pragma unroll 16
        for (int i = 0; i < 64; ++i) {
            float wr = sW[i][o][0], wi = sW[i][o][1];
            float xr = sXr[b_local][i], xi = sXi[b_local][i];
            sre += xr * wr - xi * wi;
            sim += xr * wi + xi * wr;
        }
        const float* ph = &phi[(b * 32 + mm) * 4 + (side ? 2 : 0)];
        float phr = ph[0], phim = ph[1];
        float Pre = sre * phr - sim * phim;
        float Pim = sre * phim + sim * phr;
        float a = fac * Pre;
        float bcoef = (slot == 0) ? 0.f : (side ? 2.f * invL * Pim : -2.f * invL * Pim);
        ushort* dst = afb + (size_t)b * 24576;
        ushort hiA = f2bf(a);
        int baseA = ((comp * 4 + mt) * 64 + lane) * 16;
        dst[baseA + e] = hiA;
        dst[baseA + 8 + e] = f2bf(a - bf2f(hiA));
        ushort hiB = f2bf(bcoef);
        int baseB = (((comp + 1) * 4 + mt) * 64 + lane) * 16;
        dst[baseB + e] = hiB;
        dst[baseB + 8 + e] = f2bf(bcoef - bf2f(hiB));
    }
}

// MFMA epilogue GEMM: out[b][c][l] = silu( sum_k A[k][c] * B[k][l] + bias2[c] ),
// B = [T(64); (-1)^l T(64); x[b](64)]. grid 2048 = b(32) x lt(64); wave: 64c x 32l.
// All paths bf16-hi only (validated scale analysis); x-loads issued early (T14).
__global__ __launch_bounds__(256, 4) void k_fuse(const float* __restrict__ x,
        const ushort* __restrict__ TFB, const ushort* __restrict__ AFB,
        const float* __restrict__ bias2, float* __restrict__ out) {
    int b = blockIdx.x >> 6, lt = blockIdx.x & 63;
    int w = threadIdx.x >> 6, lane = threadIdx.x & 63;
    int col = lane & 15, kgrp = lane >> 4;
    int lbase = lt * 128 + w * 32;
    int lt0 = lbase >> 4;
    const i32x4* tb = (const i32x4*)TFB;
    const i32x4* ab = (const i32x4*)AFB + (size_t)b * 3072;

    f32x4 acc[4][2];
    #pragma unroll
    for (int i = 0; i < 4; ++i)
        #pragma unroll
        for (int j = 0; j < 2; ++j) acc[i][j] = (f32x4){0.f, 0.f, 0.f, 0.f};

    int sm = (col & 1) ? (int)0x80008000 : 0;
    i32x4 SM = {sm, sm, sm, sm};

    auto tpart = [&](int ts) {
        i32x4 bh[2];
        #pragma unroll
        for (int nj = 0; nj < 2; ++nj)
            bh[nj] = tb[((lt0 + nj) * 2 + ts) * 64 + lane];
        #pragma unroll
        for (int mt = 0; mt < 4; ++mt) {
            i32x4 ah0 = ab[((ts * 4 + mt) * 64 + lane) * 2];
            i32x4 ah1 = ab[(((2 + ts) * 4 + mt) * 64 + lane) * 2];
            bf16x8 AH0 = asbf(ah0), AH1 = asbf(ah1);
            #pragma unroll
            for (int nj = 0; nj < 2; ++nj) {
                acc[mt][nj] = MFMA(AH0, asbf(bh[nj]), acc[mt][nj]);
                acc[mt][nj] = MFMA(AH1, asbf(bh[nj] ^ SM), acc[mt][nj]);
            }
        }
    };
    auto xissue = [&](int ts, float xv[2][8]) {
        #pragma unroll
        for (int nj = 0; nj < 2; ++nj) {
            const float* xp = x + (size_t)(b * 64 + ts * 32 + kgrp * 8) * L_ + lbase + nj * 16 + col;
            #pragma unroll
            for (int e = 0; e < 8; ++e) xv[nj][e] = xp[(size_t)e * L_];
        }
    };
    auto xpart = [&](int ts, float xv[2][8]) {
        #pragma unroll
        for (int nj = 0; nj < 2; ++nj) {
            int h0 = pkbf(xv[nj][0], xv[nj][1]), h1 = pkbf(xv[nj][2], xv[nj][3]);
            int h2 = pkbf(xv[nj][4], xv[nj][5]), h3 = pkbf(xv[nj][6], xv[nj][7]);
            bf16x8 XH = asbf((i32x4){h0, h1, h2, h3});
            #pragma unroll
            for (int mt = 0; mt < 4; ++mt) {
                i32x4 ah = ab[(((4 + ts) * 4 + mt) * 64 + lane) * 2];
                acc[mt][nj] = MFMA(asbf(ah), XH, acc[mt][nj]);
            }
        }
    };

    float xva[2][8], xvb[2][8];
    xissue(0, xva);          // x-loads ts=0 in flight
    tpart(0);                // MFMAs overlap
    xissue(1, xvb);          // x-loads ts=1 in flight
    xpart(0, xva);           // consume ts=0
    tpart(1);                // MFMAs overlap ts=1 loads
    xpart(1, xvb);

    #pragma unroll
    for (int mt = 0; mt < 4; ++mt) {
        #pragma unroll
        for (int r = 0; r < 4; ++r) {
            int c = mt * 16 + kgrp * 4 + r;
            float bias = bias2[b * 64 + c];
            float* op = out + (size_t)(b * 64 + c) * L_ + lbase + col;
            #pragma unroll
            for (int nj = 0; nj < 2; ++nj) {
                float v = acc[mt][nj][r] + bias;
                op[nj * 16] = v / (1.f + __expf(-v));
            }
        }
    }
}

extern "C" void kernel_launch(void* const* d_in, const int* in_sizes, int n_in,
                              void* d_out, int out_size, void* d_ws, size_t ws_size,
                              hipStream_t stream) {
    const float* x    = (const float*)d_in[0];
    const float* emb  = (const float*)d_in[1];
    const float* wpos = (const float*)d_in[2];
    const float* wneg = (const float*)d_in[3];
    const float* Arp  = (const float*)d_in[4];
    const float* Aip  = (const float*)d_in[5];
    const float* Arn  = (const float*)d_in[6];
    const float* Ain  = (const float*)d_in[7];
    const float* w1   = (const float*)d_in[8];
    const float* b1   = (const float*)d_in[9];
    const float* w2   = (const float*)d_in[10];
    const float* b2   = (const float*)d_in[11];
    const float* lw   = (const float*)d_in[12];
    const float* lb   = (const float*)d_in[13];
    float* out = (float*)d_out;
    float* ws = (float*)d_ws;
    ushort* TFB  = (ushort*)(ws + OFF_TFB);
    ushort* TLB  = (ushort*)(ws + OFF_TLB);
    ushort* AFB  = (ushort*)(ws + OFF_AFB);
    float*  XFRP = ws + OFF_XFRP;
    float*  B2   = ws + OFF_B2;
    float*  PHI  = ws + OFF_PHI;
    float*  GB   = ws + OFF_GB;

    hipLaunchKernelGGL(k_init,  dim3(4144), dim3(256), 0, stream,
                       TLB, TFB, emb, Arp, Aip, Arn, Ain, PHI, w1, b1, w2, b2, GB);
    hipLaunchKernelGGL(k_dft,   dim3(1024), dim3(256), 0, stream, x, TLB, XFRP);
    hipLaunchKernelGGL(k_mix,   dim3(160),  dim3(256), 0, stream, XFRP, wpos, wneg, PHI,
                       lw, lb, GB, AFB, B2);
    hipLaunchKernelGGL(k_fuse,  dim3(2048), dim3(256), 0, stream, x, TFB, AFB, B2, out);
}

// Round 14
// 69.112 us; speedup vs baseline: 1.0537x; 1.0537x over previous
//
#include <hip/hip_runtime.h>
#include <math.h>

#define L_ 8192
#define EMB_ 256
#define HID_ 64

typedef __attribute__((ext_vector_type(8))) short bf16x8;
typedef __attribute__((ext_vector_type(4))) float f32x4;
typedef __attribute__((ext_vector_type(4))) int i32x4;

// workspace layout (floats)
#define OFF_TFB  0           // ushort[512][2][64][8]  synthesis B-frags, hi only
#define OFF_TLB  262144      // ushort[256][4][64][8]  analysis B-frags, hi only
#define OFF_AFB  524288      // ushort[32][6][4][64][16] A-frags (hi+lo)
#define OFF_XFRP 917504      // float[8][128][2048] per-Kseg DFT partials, transposed
#define OFF_B2   3014656     // float[32*64]
#define OFF_PHI  3016704     // float[32*32*4]
#define OFF_GB   3020800     // float2[32*64]

__device__ inline int pkbf(float a, float b) {
    int r;
    asm volatile("v_cvt_pk_bf16_f32 %0, %1, %2" : "=v"(r) : "v"(a), "v"(b));
    return r;
}
__device__ inline bf16x8 asbf(i32x4 v) { union { i32x4 i; bf16x8 h; } u; u.i = v; return u.h; }
#define MFMA(A,B,C) __builtin_amdgcn_mfma_f32_16x16x32_bf16((A),(B),(C),0,0,0)

__device__ inline ushort f2bf(float v) {
    unsigned b = __float_as_uint(v);
    return (ushort)((b + 0x7FFFu + ((b >> 16) & 1u)) >> 16);
}
__device__ inline float bf2f(ushort h) { return __uint_as_float(((unsigned)h) << 16); }
// hardware trig: input in REVOLUTIONS (D = sin/cos(S0 * 2pi)); arg r/8192 is already reduced
__device__ inline float hwsin(float rev) { float r; asm("v_sin_f32 %0, %1" : "=v"(r) : "v"(rev)); return r; }
__device__ inline float hwcos(float rev) { float r; asm("v_cos_f32 %0, %1" : "=v"(r) : "v"(rev)); return r; }

// merged: trig tables (blocks 0..4095) + phi (4096..4111) + mlp (4112..4143)
__global__ __launch_bounds__(256) void k_init(ushort* __restrict__ TLB, ushort* __restrict__ TFB,
        const float* __restrict__ emb,
        const float* __restrict__ Arp, const float* __restrict__ Aip,
        const float* __restrict__ Arn, const float* __restrict__ Ain, float* __restrict__ phi,
        const float* __restrict__ w1, const float* __restrict__ b1,
        const float* __restrict__ w2, const float* __restrict__ b2, float* __restrict__ gb) {
    int bid = blockIdx.x;
    if (bid < 4096) {
        int idx = bid * 256 + threadIdx.x;   // 0..1048575
        int f, l; ushort* dst;
        if (idx < 524288) {                  // TLB: [kstep 256][ct 4][lane 64][e 8]
            int u = idx;
            int e = u & 7, lane = (u >> 3) & 63, ct = (u >> 9) & 3, kstep = u >> 11;
            l = kstep * 32 + ((lane >> 4) << 3) + e;
            f = ct * 16 + (lane & 15);
            dst = TLB + u;
        } else {                             // TFB: [lt 512][ts 2][lane 64][e 8]
            int u = idx - 524288;
            int e = u & 7, lane = (u >> 3) & 63, ts = (u >> 9) & 1, lt = u >> 10;
            l = lt * 16 + (lane & 15);
            f = ts * 32 + ((lane >> 4) << 3) + e;
            dst = TFB + u;
        }
        int fr = f & 31; bool sinp = (f & 32) != 0;
        int r = (fr * l) & (L_ - 1);
        float rev = (float)r * (1.0f / (float)L_);
        float v = sinp ? hwsin(rev) : hwcos(rev);
        *dst = f2bf(v);
    } else if (bid < 4112) {
        int tid = (bid - 4096) * 256 + threadIdx.x;   // (b*32+mm)*4+cmp
        int b = tid >> 7;
        int mm = (tid >> 2) & 31;
        int cmp = tid & 3;
        const float* A = (cmp == 0) ? Arp : (cmp == 1) ? Aip : (cmp == 2) ? Arn : Ain;
        const float4* e4 = (const float4*)(emb + b * EMB_);
        const float4* a4 = (const float4*)(A + mm * EMB_);
        float acc = 0.f;
        for (int q = 0; q < EMB_ / 4; ++q) {
            float4 ev = e4[q], av = a4[q];
            acc += ev.x * av.x + ev.y * av.y + ev.z * av.z + ev.w * av.w;
        }
        phi[tid] = acc;
    } else {
        __shared__ float h[HID_];
        int b = bid - 4112, t = threadIdx.x;
        if (t < HID_) {
            const float4* e4 = (const float4*)(emb + b * EMB_);
            const float4* w4 = (const float4*)(w1 + t * EMB_);
            float acc = b1[t];
            for (int q = 0; q < EMB_ / 4; ++q) {
                float4 ev = e4[q], wv = w4[q];
                acc += ev.x * wv.x + ev.y * wv.y + ev.z * wv.z + ev.w * wv.w;
            }
            h[t] = acc / (1.f + expf(-acc));
        }
        __syncthreads();
        if (t < 128) {
            float g = b2[t];
            const float4* h4 = (const float4*)h;
            const float4* w4 = (const float4*)(w2 + t * HID_);
            for (int q = 0; q < HID_ / 4; ++q) {
                float4 hv = h4[q], wv = w4[q];
                g += hv.x * wv.x + hv.y * wv.y + hv.z * wv.z + hv.w * wv.w;
            }
            if (t < 64) gb[(b * 64 + t) * 2 + 0] = 1.f + g;
            else        gb[(b * 64 + (t - 64)) * 2 + 1] = g;
        }
    }
}

// single-bf16 MFMA DFT; grid 1024 = stripe(128: 16 rows) x lseg(8: K=1024); 4 waves split K
// depth-3 x prefetch + 1-deep TLB prefetch; stores transposed partials xfrp[lseg][col][row]
__global__ __launch_bounds__(256) void k_dft(const float* __restrict__ x,
        const ushort* __restrict__ TLB, float* __restrict__ xfrp) {
    __shared__ float sP[4][16][132];
    int stripe = blockIdx.x >> 3;
    int lseg = blockIdx.x & 7;
    int w = threadIdx.x >> 6;
    int lane = threadIdx.x & 63;
    int row = lane & 15, koff = (lane >> 4) << 3;
    int r0 = stripe * 16;
    int kb0 = lseg * 1024 + w * 256;

    f32x4 acc[8];
    #pragma unroll
    for (int i = 0; i < 8; ++i) acc[i] = (f32x4){0.f, 0.f, 0.f, 0.f};

    const float* ap = x + (size_t)(r0 + row) * L_ + kb0 + koff;
    const i32x4* tb = (const i32x4*)TLB;
    int tbase = (kb0 >> 5) * 256 + lane;    // i32x4 index; +256 per kstep, +64 per ct
    const i32x4 SM = {(int)0x80000000, (int)0x80000000, (int)0x80000000, (int)0x80000000};

    float4 xa0 = *(const float4*)(ap);
    float4 xc0 = *(const float4*)(ap + 4);
    float4 xa1 = *(const float4*)(ap + 32);
    float4 xc1 = *(const float4*)(ap + 36);
    float4 xa2 = *(const float4*)(ap + 64);
    float4 xc2 = *(const float4*)(ap + 68);
    i32x4 t0 = tb[tbase], t1 = tb[tbase + 64], t2 = tb[tbase + 128], t3 = tb[tbase + 192];
    #pragma unroll
    for (int ks = 0; ks < 8; ++ks) {
        float4 nxa = {0,0,0,0}, nxc = {0,0,0,0};
        i32x4 n0 = t0, n1 = t1, n2 = t2, n3 = t3;
        if (ks < 5) {
            nxa = *(const float4*)(ap + (ks + 3) * 32);
            nxc = *(const float4*)(ap + (ks + 3) * 32 + 4);
        }
        if (ks < 7) {
            int ti = tbase + (ks + 1) * 256;
            n0 = tb[ti]; n1 = tb[ti + 64]; n2 = tb[ti + 128]; n3 = tb[ti + 192];
        }
        int h0 = pkbf(xa0.x, xa0.y), h1 = pkbf(xa0.z, xa0.w);
        int h2 = pkbf(xc0.x, xc0.y), h3 = pkbf(xc0.z, xc0.w);
        bf16x8 AH = asbf((i32x4){h0, h1, h2, h3});
        acc[0] = MFMA(AH, asbf(t0), acc[0]); acc[4] = MFMA(AH, asbf(t0 ^ SM), acc[4]);
        acc[1] = MFMA(AH, asbf(t1), acc[1]); acc[5] = MFMA(AH, asbf(t1 ^ SM), acc[5]);
        acc[2] = MFMA(AH, asbf(t2), acc[2]); acc[6] = MFMA(AH, asbf(t2 ^ SM), acc[6]);
        acc[3] = MFMA(AH, asbf(t3), acc[3]); acc[7] = MFMA(AH, asbf(t3 ^ SM), acc[7]);
        xa0 = xa1; xc0 = xc1; xa1 = xa2; xc1 = xc2; xa2 = nxa; xc2 = nxc;
        t0 = n0; t1 = n1; t2 = n2; t3 = n3;
    }
    int crow = (lane >> 4) << 2;
    int ccol = lane & 15;
    #pragma unroll
    for (int ct = 0; ct < 8; ++ct)
        #pragma unroll
        for (int r = 0; r < 4; ++r)
            sP[w][crow + r][ct * 16 + ccol] = acc[ct][r];
    __syncthreads();
    #pragma unroll
    for (int i = 0; i < 8; ++i) {
        int e = threadIdx.x + 256 * i;     // 0..2047
        int rr = e & 15, cc = e >> 4;
        float s = sP[0][rr][cc] + sP[1][rr][cc] + sP[2][rr][cc] + sP[3][rr][cc];
        xfrp[((size_t)(lseg * 128 + cc)) * 2048 + r0 + rr] = s;
    }
}

// mode mixing -> AFB fragments directly.
// blocks 0..255: [mm 32][side 2][bh 4] spectral rows (8 b each); blocks 256..287: Ax fold + bias2
__global__ __launch_bounds__(256) void k_mix(const float* __restrict__ xfrt,
        const float* __restrict__ wpos, const float* __restrict__ wneg,
        const float* __restrict__ phi, const float* __restrict__ lw,
        const float* __restrict__ lb, const float* __restrict__ gb,
        ushort* __restrict__ afb, float* __restrict__ bias2) {
    int bi = blockIdx.x;
    int tid = threadIdx.x;
    if (bi >= 256) {                 // Ax fold + bias2
        int b = bi - 256;
        ushort* dst = afb + (size_t)b * 24576;
        #pragma unroll
        for (int j = 0; j < 16; ++j) {
            int u = tid + 256 * j;   // 0..4095 : [ks2 2][mt 4][lane 64][e 8]
            int e = u & 7, lane = (u >> 3) & 63, mt = (u >> 9) & 3, ks2 = u >> 11;
            int c = mt * 16 + (lane & 15);
            int kk = ((lane >> 4) << 3) + e;
            float v = lw[c * 64 + ks2 * 32 + kk] * gb[(b * 64 + c) * 2];
            ushort hi = f2bf(v);
            int base = (((4 + ks2) * 4 + mt) * 64 + lane) * 16;
            dst[base + e] = hi;
            dst[base + 8 + e] = f2bf(v - bf2f(hi));
        }
        if (tid < 64) {
            float g1 = gb[(b * 64 + tid) * 2], be = gb[(b * 64 + tid) * 2 + 1];
            bias2[b * 64 + tid] = lb[tid] * g1 + be;
        }
        return;
    }
    __shared__ float sW[64][64][2];     // [i][o][re/im]
    __shared__ float sXr[8][64], sXi[8][64];   // [b_local][i]
    int bh = bi & 3, side = (bi >> 2) & 1, mm = bi >> 3;
    int slot = side ? (31 - mm) : mm;
    int colR = side ? (64 + slot) : mm;
    int colI = side ? (96 + slot) : (32 + mm);

    const float* W = side ? wneg : wpos;
    #pragma unroll
    for (int j = 0; j < 16; ++j) {
        int fidx = tid + 256 * j;       // 0..4095 = i*64+o
        int i = fidx >> 6, o = fidx & 63;
        float2 wv = *(const float2*)&W[(size_t)(i * 64 + o) * 64 + mm * 2];
        sW[i][o][0] = wv.x;
        sW[i][o][1] = wv.y;
    }
    {   // stage 8 b x 64 i sums (512 floats per component) via float2 per thread
        const float2* pR = (const float2*)(xfrt + (size_t)colR * 2048 + bh * 512);
        const float2* pI = (const float2*)(xfrt + (size_t)colI * 2048 + bh * 512);
        float2 aR = {0, 0}, aI = {0, 0};
        #pragma unroll
        for (int s = 0; s < 8; ++s) {
            float2 vR = pR[(size_t)s * 131072 + tid];
            float2 vI = pI[(size_t)s * 131072 + tid];
            aR.x += vR.x; aR.y += vR.y;
            aI.x += vI.x; aI.y += vI.y;
        }
        if (!side) { aI.x = -aI.x; aI.y = -aI.y; }
        *(float2*)&sXr[tid >> 5][(tid & 31) * 2] = aR;
        *(float2*)&sXi[tid >> 5][(tid & 31) * 2] = aI;
    }
    __syncthreads();

    int o = tid & 63, bg = tid >> 6;
    const float invL = 1.f / (float)L_;
    float fac = (slot == 0) ? invL : 2.f * invL;
    int comp = side ? 2 : 0;
    int e = slot & 7, kgrp = slot >> 3;
    int mt = o >> 4, lane = kgrp * 16 + (o & 15);
    #pragma unroll
    for (int bl = 0; bl < 2; ++bl) {
        int b_local = bg * 2 + bl;
        int b = bh * 8 + b_local;
        float sre = 0.f, sim = 0.f;
        #pragma unroll 16
        for (int i = 0; i < 64; ++i) {
            float wr = sW[i][o][0], wi = sW[i][o][1];
            float xr = sXr[b_local][i], xi = sXi[b_local][i];
            sre += xr * wr - xi * wi;
            sim += xr * wi + xi * wr;
        }
        const float* ph = &phi[(b * 32 + mm) * 4 + (side ? 2 : 0)];
        float phr = ph[0], phim = ph[1];
        float Pre = sre * phr - sim * phim;
        float Pim = sre * phim + sim * phr;
        float a = fac * Pre;
        float bcoef = (slot == 0) ? 0.f : (side ? 2.f * invL * Pim : -2.f * invL * Pim);
        ushort* dst = afb + (size_t)b * 24576;
        ushort hiA = f2bf(a);
        int baseA = ((comp * 4 + mt) * 64 + lane) * 16;
        dst[baseA + e] = hiA;
        dst[baseA + 8 + e] = f2bf(a - bf2f(hiA));
        ushort hiB = f2bf(bcoef);
        int baseB = (((comp + 1) * 4 + mt) * 64 + lane) * 16;
        dst[baseB + e] = hiB;
        dst[baseB + 8 + e] = f2bf(bcoef - bf2f(hiB));
    }
}

// MFMA epilogue GEMM: out[b][c][l] = silu( sum_k A[k][c] * B[k][l] + bias2[c] ),
// B = [T(64); (-1)^l T(64); x[b](64)]. grid 2048 = b(32) x lt(64); wave: 64c x 32l.
// Macro-inlined schedule (no lambda array params); both x-load batches issued up front.
#define XISSUE(ts, xv)                                                                   \
    _Pragma("unroll")                                                                    \
    for (int nj = 0; nj < 2; ++nj) {                                                     \
        const float* xp = x + (size_t)(b * 64 + (ts) * 32 + kgrp * 8) * L_               \
                            + lbase + nj * 16 + col;                                     \
        _Pragma("unroll")                                                                \
        for (int e = 0; e < 8; ++e) xv[nj][e] = xp[(size_t)e * L_];                      \
    }

#define TPART(ts)                                                                        \
    {                                                                                    \
        i32x4 bh_[2];                                                                    \
        _Pragma("unroll")                                                                \
        for (int nj = 0; nj < 2; ++nj)                                                   \
            bh_[nj] = tb[((lt0 + nj) * 2 + (ts)) * 64 + lane];                           \
        _Pragma("unroll")                                                                \
        for (int mt = 0; mt < 4; ++mt) {                                                 \
            i32x4 ah0 = ab[(((ts) * 4 + mt) * 64 + lane) * 2];                           \
            i32x4 ah1 = ab[(((2 + (ts)) * 4 + mt) * 64 + lane) * 2];                     \
            bf16x8 AH0 = asbf(ah0), AH1 = asbf(ah1);                                     \
            _Pragma("unroll")                                                            \
            for (int nj = 0; nj < 2; ++nj) {                                             \
                acc[mt][nj] = MFMA(AH0, asbf(bh_[nj]), acc[mt][nj]);                     \
                acc[mt][nj] = MFMA(AH1, asbf(bh_[nj] ^ SM), acc[mt][nj]);                \
            }                                                                            \
        }                                                                                \
    }

#define XPART(ts, xv)                                                                    \
    _Pragma("unroll")                                                                    \
    for (int nj = 0; nj < 2; ++nj) {                                                     \
        int h0 = pkbf(xv[nj][0], xv[nj][1]), h1 = pkbf(xv[nj][2], xv[nj][3]);            \
        int h2 = pkbf(xv[nj][4], xv[nj][5]), h3 = pkbf(xv[nj][6], xv[nj][7]);            \
        bf16x8 XH = asbf((i32x4){h0, h1, h2, h3});                                       \
        _Pragma("unroll")                                                                \
        for (int mt = 0; mt < 4; ++mt) {                                                 \
            i32x4 ah = ab[(((4 + (ts)) * 4 + mt) * 64 + lane) * 2];                      \
            acc[mt][nj] = MFMA(asbf(ah), XH, acc[mt][nj]);                               \
        }                                                                                \
    }

__global__ __launch_bounds__(256, 3) void k_fuse(const float* __restrict__ x,
        const ushort* __restrict__ TFB, const ushort* __restrict__ AFB,
        const float* __restrict__ bias2, float* __restrict__ out) {
    int b = blockIdx.x >> 6, lt = blockIdx.x & 63;
    int w = threadIdx.x >> 6, lane = threadIdx.x & 63;
    int col = lane & 15, kgrp = lane >> 4;
    int lbase = lt * 128 + w * 32;
    int lt0 = lbase >> 4;
    const i32x4* tb = (const i32x4*)TFB;
    const i32x4* ab = (const i32x4*)AFB + (size_t)b * 3072;

    f32x4 acc[4][2];
    #pragma unroll
    for (int i = 0; i < 4; ++i)
        #pragma unroll
        for (int j = 0; j < 2; ++j) acc[i][j] = (f32x4){0.f, 0.f, 0.f, 0.f};

    int sm = (col & 1) ? (int)0x80008000 : 0;
    i32x4 SM = {sm, sm, sm, sm};

    float xva[2][8], xvb[2][8];
    XISSUE(0, xva)           // 32 loads in flight
    XISSUE(1, xvb)           // +32 loads in flight
    TPART(0)                 // 16 MFMAs cover ts=0 loads
    XPART(0, xva)
    TPART(1)                 // ts=1 loads covered by ~40 MFMAs by now
    XPART(1, xvb)

    #pragma unroll
    for (int mt = 0; mt < 4; ++mt) {
        #pragma unroll
        for (int r = 0; r < 4; ++r) {
            int c = mt * 16 + kgrp * 4 + r;
            float bias = bias2[b * 64 + c];
            float* op = out + (size_t)(b * 64 + c) * L_ + lbase + col;
            #pragma unroll
            for (int nj = 0; nj < 2; ++nj) {
                float v = acc[mt][nj][r] + bias;
                op[nj * 16] = v / (1.f + __expf(-v));
            }
        }
    }
}

extern "C" void kernel_launch(void* const* d_in, const int* in_sizes, int n_in,
                              void* d_out, int out_size, void* d_ws, size_t ws_size,
                              hipStream_t stream) {
    const float* x    = (const float*)d_in[0];
    const float* emb  = (const float*)d_in[1];
    const float* wpos = (const float*)d_in[2];
    const float* wneg = (const float*)d_in[3];
    const float* Arp  = (const float*)d_in[4];
    const float* Aip  = (const float*)d_in[5];
    const float* Arn  = (const float*)d_in[6];
    const float* Ain  = (const float*)d_in[7];
    const float* w1   = (const float*)d_in[8];
    const float* b1   = (const float*)d_in[9];
    const float* w2   = (const float*)d_in[10];
    const float* b2   = (const float*)d_in[11];
    const float* lw   = (const float*)d_in[12];
    const float* lb   = (const float*)d_in[13];
    float* out = (float*)d_out;
    float* ws = (float*)d_ws;
    ushort* TFB  = (ushort*)(ws + OFF_TFB);
    ushort* TLB  = (ushort*)(ws + OFF_TLB);
    ushort* AFB  = (ushort*)(ws + OFF_AFB);
    float*  XFRP = ws + OFF_XFRP;
    float*  B2   = ws + OFF_B2;
    float*  PHI  = ws + OFF_PHI;
    float*  GB   = ws + OFF_GB;

    hipLaunchKernelGGL(k_init,  dim3(4144), dim3(256), 0, stream,
                       TLB, TFB, emb, Arp, Aip, Arn, Ain, PHI, w1, b1, w2, b2, GB);
    hipLaunchKernelGGL(k_dft,   dim3(1024), dim3(256), 0, stream, x, TLB, XFRP);
    hipLaunchKernelGGL(k_mix,   dim3(288),  dim3(256), 0, stream, XFRP, wpos, wneg, PHI,
                       lw, lb, GB, AFB, B2);
    hipLaunchKernelGGL(k_fuse,  dim3(2048), dim3(256), 0, stream, x, TFB, AFB, B2, out);
}

// Round 15
// 67.506 us; speedup vs baseline: 1.0788x; 1.0238x over previous
//
#include <hip/hip_runtime.h>
#include <math.h>

#define L_ 8192
#define EMB_ 256
#define HID_ 64

typedef __attribute__((ext_vector_type(8))) short bf16x8;
typedef __attribute__((ext_vector_type(4))) float f32x4;
typedef __attribute__((ext_vector_type(4))) int i32x4;

// workspace layout (floats)
#define OFF_TFB  0           // ushort[512][2][64][8]  synthesis B-frags, hi only
#define OFF_TLB  262144      // ushort[256][4][64][8]  analysis B-frags, hi only
#define OFF_AFB  524288      // ushort[32][6][4][64][16] A-frags (hi+lo)
#define OFF_XFRP 917504      // float[8][128][2048] per-Kseg DFT partials, transposed
#define OFF_B2   3014656     // float[32*64]
#define OFF_PHI  3016704     // float[32*32*4]
#define OFF_GB   3020800     // float2[32*64]
#define OFF_WT   3024896     // float[2][32][64][64][2] transposed mix weights (2 MB)
#define OFF_XT   3549184     // ushort[128][8192][16] bf16 x, frag-transposed (33.5 MB)

__device__ inline int pkbf(float a, float b) {
    int r;
    asm volatile("v_cvt_pk_bf16_f32 %0, %1, %2" : "=v"(r) : "v"(a), "v"(b));
    return r;
}
__device__ inline bf16x8 asbf(i32x4 v) { union { i32x4 i; bf16x8 h; } u; u.i = v; return u.h; }
#define MFMA(A,B,C) __builtin_amdgcn_mfma_f32_16x16x32_bf16((A),(B),(C),0,0,0)

__device__ inline ushort f2bf(float v) {
    unsigned b = __float_as_uint(v);
    return (ushort)((b + 0x7FFFu + ((b >> 16) & 1u)) >> 16);
}
__device__ inline float bf2f(ushort h) { return __uint_as_float(((unsigned)h) << 16); }
// hardware trig: input in REVOLUTIONS; arg r/8192 is already reduced
__device__ inline float hwsin(float rev) { float r; asm("v_sin_f32 %0, %1" : "=v"(r) : "v"(rev)); return r; }
__device__ inline float hwcos(float rev) { float r; asm("v_cos_f32 %0, %1" : "=v"(r) : "v"(rev)); return r; }

// merged init: trig (0..4095) + phi (4096..4111) + mlp (4112..4143) + W-transpose (4144..4271)
__global__ __launch_bounds__(256) void k_init(ushort* __restrict__ TLB, ushort* __restrict__ TFB,
        const float* __restrict__ emb,
        const float* __restrict__ Arp, const float* __restrict__ Aip,
        const float* __restrict__ Arn, const float* __restrict__ Ain, float* __restrict__ phi,
        const float* __restrict__ w1, const float* __restrict__ b1,
        const float* __restrict__ w2, const float* __restrict__ b2, float* __restrict__ gb,
        const float* __restrict__ wpos, const float* __restrict__ wneg, float* __restrict__ WT) {
    int bid = blockIdx.x;
    if (bid < 4096) {
        int idx = bid * 256 + threadIdx.x;   // 0..1048575
        int f, l; ushort* dst;
        if (idx < 524288) {                  // TLB: [kstep 256][ct 4][lane 64][e 8]
            int u = idx;
            int e = u & 7, lane = (u >> 3) & 63, ct = (u >> 9) & 3, kstep = u >> 11;
            l = kstep * 32 + ((lane >> 4) << 3) + e;
            f = ct * 16 + (lane & 15);
            dst = TLB + u;
        } else {                             // TFB: [lt 512][ts 2][lane 64][e 8]
            int u = idx - 524288;
            int e = u & 7, lane = (u >> 3) & 63, ts = (u >> 9) & 1, lt = u >> 10;
            l = lt * 16 + (lane & 15);
            f = ts * 32 + ((lane >> 4) << 3) + e;
            dst = TFB + u;
        }
        int fr = f & 31; bool sinp = (f & 32) != 0;
        int r = (fr * l) & (L_ - 1);
        float rev = (float)r * (1.0f / (float)L_);
        float v = sinp ? hwsin(rev) : hwcos(rev);
        *dst = f2bf(v);
    } else if (bid < 4112) {
        int tid = (bid - 4096) * 256 + threadIdx.x;   // (b*32+mm)*4+cmp
        int b = tid >> 7;
        int mm = (tid >> 2) & 31;
        int cmp = tid & 3;
        const float* A = (cmp == 0) ? Arp : (cmp == 1) ? Aip : (cmp == 2) ? Arn : Ain;
        const float4* e4 = (const float4*)(emb + b * EMB_);
        const float4* a4 = (const float4*)(A + mm * EMB_);
        float acc = 0.f;
        for (int q = 0; q < EMB_ / 4; ++q) {
            float4 ev = e4[q], av = a4[q];
            acc += ev.x * av.x + ev.y * av.y + ev.z * av.z + ev.w * av.w;
        }
        phi[tid] = acc;
    } else if (bid < 4144) {
        __shared__ float h[HID_];
        int b = bid - 4112, t = threadIdx.x;
        if (t < HID_) {
            const float4* e4 = (const float4*)(emb + b * EMB_);
            const float4* w4 = (const float4*)(w1 + t * EMB_);
            float acc = b1[t];
            for (int q = 0; q < EMB_ / 4; ++q) {
                float4 ev = e4[q], wv = w4[q];
                acc += ev.x * wv.x + ev.y * wv.y + ev.z * wv.z + ev.w * wv.w;
            }
            h[t] = acc / (1.f + expf(-acc));
        }
        __syncthreads();
        if (t < 128) {
            float g = b2[t];
            const float4* h4 = (const float4*)h;
            const float4* w4 = (const float4*)(w2 + t * HID_);
            for (int q = 0; q < HID_ / 4; ++q) {
                float4 hv = h4[q], wv = w4[q];
                g += hv.x * wv.x + hv.y * wv.y + hv.z * wv.z + hv.w * wv.w;
            }
            if (t < 64) gb[(b * 64 + t) * 2 + 0] = 1.f + g;
            else        gb[(b * 64 + (t - 64)) * 2 + 1] = g;
        }
    } else {
        // W transpose: W[i][o][mm][ri] -> WT[side][mm][i][o][ri]
        int t = bid - 4144;              // 0..127
        int side = t >> 6, i = t & 63;
        const float* W = side ? wneg : wpos;
        const float* src = W + (size_t)i * 4096;
        int tid = threadIdx.x;
        #pragma unroll
        for (int j = 0; j < 8; ++j) {
            int u = tid + 256 * j;       // 0..2047 float2 units: mm = u>>6, o = u&63
            int mm = u >> 6, o = u & 63;
            float2 v = *(const float2*)(src + o * 64 + mm * 2);
            *(float2*)(WT + ((size_t)(side * 32 + mm)) * 8192 + i * 128 + o * 2) = v;
        }
    }
}

// single-bf16 MFMA DFT; grid 1024 = stripe(128: 16 rows) x lseg(8: K=1024); 4 waves split K
// also writes XT[stripe][l][c16] bf16 copy of x for k_fuse's dense B-frag loads
__global__ __launch_bounds__(256) void k_dft(const float* __restrict__ x,
        const ushort* __restrict__ TLB, float* __restrict__ xfrp, ushort* __restrict__ XT) {
    __shared__ float sP[4][16][132];
    int stripe = blockIdx.x >> 3;
    int lseg = blockIdx.x & 7;
    int w = threadIdx.x >> 6;
    int lane = threadIdx.x & 63;
    int row = lane & 15, koff = (lane >> 4) << 3;
    int r0 = stripe * 16;
    int kb0 = lseg * 1024 + w * 256;

    f32x4 acc[8];
    #pragma unroll
    for (int i = 0; i < 8; ++i) acc[i] = (f32x4){0.f, 0.f, 0.f, 0.f};

    const float* ap = x + (size_t)(r0 + row) * L_ + kb0 + koff;
    const i32x4* tb = (const i32x4*)TLB;
    int tbase = (kb0 >> 5) * 256 + lane;    // i32x4 index; +256 per kstep, +64 per ct
    const i32x4 SM = {(int)0x80000000, (int)0x80000000, (int)0x80000000, (int)0x80000000};

    float4 xa0 = *(const float4*)(ap);
    float4 xc0 = *(const float4*)(ap + 4);
    float4 xa1 = *(const float4*)(ap + 32);
    float4 xc1 = *(const float4*)(ap + 36);
    float4 xa2 = *(const float4*)(ap + 64);
    float4 xc2 = *(const float4*)(ap + 68);
    i32x4 t0 = tb[tbase], t1 = tb[tbase + 64], t2 = tb[tbase + 128], t3 = tb[tbase + 192];
    #pragma unroll
    for (int ks = 0; ks < 8; ++ks) {
        float4 nxa = {0,0,0,0}, nxc = {0,0,0,0};
        i32x4 n0 = t0, n1 = t1, n2 = t2, n3 = t3;
        if (ks < 5) {
            nxa = *(const float4*)(ap + (ks + 3) * 32);
            nxc = *(const float4*)(ap + (ks + 3) * 32 + 4);
        }
        if (ks < 7) {
            int ti = tbase + (ks + 1) * 256;
            n0 = tb[ti]; n1 = tb[ti + 64]; n2 = tb[ti + 128]; n3 = tb[ti + 192];
        }
        int h0 = pkbf(xa0.x, xa0.y), h1 = pkbf(xa0.z, xa0.w);
        int h2 = pkbf(xc0.x, xc0.y), h3 = pkbf(xc0.z, xc0.w);
        bf16x8 AH = asbf((i32x4){h0, h1, h2, h3});
        // bf16 x copy in frag-transposed layout: XT[(stripe*8192 + l)*16 + row]
        {
            ushort* xtp = XT + (((size_t)stripe * 8192 + kb0 + koff + ks * 32) << 4) + row;
            xtp[0]   = (ushort)h0;  xtp[16]  = (ushort)((unsigned)h0 >> 16);
            xtp[32]  = (ushort)h1;  xtp[48]  = (ushort)((unsigned)h1 >> 16);
            xtp[64]  = (ushort)h2;  xtp[80]  = (ushort)((unsigned)h2 >> 16);
            xtp[96]  = (ushort)h3;  xtp[112] = (ushort)((unsigned)h3 >> 16);
        }
        acc[0] = MFMA(AH, asbf(t0), acc[0]); acc[4] = MFMA(AH, asbf(t0 ^ SM), acc[4]);
        acc[1] = MFMA(AH, asbf(t1), acc[1]); acc[5] = MFMA(AH, asbf(t1 ^ SM), acc[5]);
        acc[2] = MFMA(AH, asbf(t2), acc[2]); acc[6] = MFMA(AH, asbf(t2 ^ SM), acc[6]);
        acc[3] = MFMA(AH, asbf(t3), acc[3]); acc[7] = MFMA(AH, asbf(t3 ^ SM), acc[7]);
        xa0 = xa1; xc0 = xc1; xa1 = xa2; xc1 = xc2; xa2 = nxa; xc2 = nxc;
        t0 = n0; t1 = n1; t2 = n2; t3 = n3;
    }
    int crow = (lane >> 4) << 2;
    int ccol = lane & 15;
    #pragma unroll
    for (int ct = 0; ct < 8; ++ct)
        #pragma unroll
        for (int r = 0; r < 4; ++r)
            sP[w][crow + r][ct * 16 + ccol] = acc[ct][r];
    __syncthreads();
    #pragma unroll
    for (int i = 0; i < 8; ++i) {
        int e = threadIdx.x + 256 * i;     // 0..2047
        int rr = e & 15, cc = e >> 4;
        float s = sP[0][rr][cc] + sP[1][rr][cc] + sP[2][rr][cc] + sP[3][rr][cc];
        xfrp[((size_t)(lseg * 128 + cc)) * 2048 + r0 + rr] = s;
    }
}

// mode mixing -> AFB fragments directly.
// blocks 0..255: [mm 32][side 2][bh 4] spectral rows (8 b each); blocks 256..287: Ax fold + bias2
__global__ __launch_bounds__(256) void k_mix(const float* __restrict__ xfrt,
        const float* __restrict__ WT,
        const float* __restrict__ phi, const float* __restrict__ lw,
        const float* __restrict__ lb, const float* __restrict__ gb,
        ushort* __restrict__ afb, float* __restrict__ bias2) {
    int bi = blockIdx.x;
    int tid = threadIdx.x;
    if (bi >= 256) {                 // Ax fold + bias2
        int b = bi - 256;
        ushort* dst = afb + (size_t)b * 24576;
        #pragma unroll
        for (int j = 0; j < 16; ++j) {
            int u = tid + 256 * j;   // 0..4095 : [ks2 2][mt 4][lane 64][e 8]
            int e = u & 7, lane = (u >> 3) & 63, mt = (u >> 9) & 3, ks2 = u >> 11;
            int c = mt * 16 + (lane & 15);
            int kk = ((lane >> 4) << 3) + e;
            float v = lw[c * 64 + ks2 * 32 + kk] * gb[(b * 64 + c) * 2];
            ushort hi = f2bf(v);
            int base = (((4 + ks2) * 4 + mt) * 64 + lane) * 16;
            dst[base + e] = hi;
            dst[base + 8 + e] = f2bf(v - bf2f(hi));
        }
        if (tid < 64) {
            float g1 = gb[(b * 64 + tid) * 2], be = gb[(b * 64 + tid) * 2 + 1];
            bias2[b * 64 + tid] = lb[tid] * g1 + be;
        }
        return;
    }
    __shared__ float sW[64][64][2];     // [i][o][re/im]
    __shared__ float sXr[8][64], sXi[8][64];   // [b_local][i]
    int bh = bi & 3, side = (bi >> 2) & 1, mm = bi >> 3;
    int slot = side ? (31 - mm) : mm;
    int colR = side ? (64 + slot) : mm;
    int colI = side ? (96 + slot) : (32 + mm);

    // stage transposed W tile: coalesced float4
    {
        const float4* wt = (const float4*)(WT + ((size_t)(side * 32 + mm)) * 8192);
        float* sWlin = &sW[0][0][0];
        #pragma unroll
        for (int j = 0; j < 8; ++j) {
            int u = tid + 256 * j;
            *(float4*)&sWlin[u * 4] = wt[u];
        }
    }
    {   // stage 8 b x 64 i sums via float2 per thread
        const float2* pR = (const float2*)(xfrt + (size_t)colR * 2048 + bh * 512);
        const float2* pI = (const float2*)(xfrt + (size_t)colI * 2048 + bh * 512);
        float2 aR = {0, 0}, aI = {0, 0};
        #pragma unroll
        for (int s = 0; s < 8; ++s) {
            float2 vR = pR[(size_t)s * 131072 + tid];
            float2 vI = pI[(size_t)s * 131072 + tid];
            aR.x += vR.x; aR.y += vR.y;
            aI.x += vI.x; aI.y += vI.y;
        }
        if (!side) { aI.x = -aI.x; aI.y = -aI.y; }
        *(float2*)&sXr[tid >> 5][(tid & 31) * 2] = aR;
        *(float2*)&sXi[tid >> 5][(tid & 31) * 2] = aI;
    }
    __syncthreads();

    int o = tid & 63, bg = tid >> 6;
    const float invL = 1.f / (float)L_;
    float fac = (slot == 0) ? invL : 2.f * invL;
    int comp = side ? 2 : 0;
    int e = slot & 7, kgrp = slot >> 3;
    int mt = o >> 4, lane = kgrp * 16 + (o & 15);
    #pragma unroll
    for (int bl = 0; bl < 2; ++bl) {
        int b_local = bg * 2 + bl;
        int b = bh * 8 + b_local;
        float sre = 0.f, sim = 0.f;
        #pragma unroll 16
        for (int i = 0; i < 64; ++i) {
            float wr = sW[i][o][0], wi = sW[i][o][1];
            float xr = sXr[b_local][i], xi = sXi[b_local][i];
            sre += xr * wr - xi * wi;
            sim += xr * wi + xi * wr;
        }
        const float* ph = &phi[(b * 32 + mm) * 4 + (side ? 2 : 0)];
        float phr = ph[0], phim = ph[1];
        float Pre = sre * phr - sim * phim;
        float Pim = sre * phim + sim * phr;
        float a = fac * Pre;
        float bcoef = (slot == 0) ? 0.f : (side ? 2.f * invL * Pim : -2.f * invL * Pim);
        ushort* dst = afb + (size_t)b * 24576;
        ushort hiA = f2bf(a);
        int baseA = ((comp * 4 + mt) * 64 + lane) * 16;
        dst[baseA + e] = hiA;
        dst[baseA + 8 + e] = f2bf(a - bf2f(hiA));
        ushort hiB = f2bf(bcoef);
        int baseB = (((comp + 1) * 4 + mt) * 64 + lane) * 16;
        dst[baseB + e] = hiB;
        dst[baseB + 8 + e] = f2bf(bcoef - bf2f(hiB));
    }
}

// MFMA epilogue GEMM: out[b][c][l] = silu( sum_k A[k][c] * B[k][l] + bias2[c] ),
// B = [T(64); (-1)^l T(64); x[b](64)]; x read from dense bf16 XT frags.
#define TPART(ts)                                                                        \
    {                                                                                    \
        i32x4 bh_[2];                                                                    \
        _Pragma("unroll")                                                                \
        for (int nj = 0; nj < 2; ++nj)                                                   \
            bh_[nj] = tb[((lt0 + nj) * 2 + (ts)) * 64 + lane];                           \
        _Pragma("unroll")                                                                \
        for (int mt = 0; mt < 4; ++mt) {                                                 \
            i32x4 ah0 = ab[(((ts) * 4 + mt) * 64 + lane) * 2];                           \
            i32x4 ah1 = ab[(((2 + (ts)) * 4 + mt) * 64 + lane) * 2];                     \
            bf16x8 AH0 = asbf(ah0), AH1 = asbf(ah1);                                     \
            _Pragma("unroll")                                                            \
            for (int nj = 0; nj < 2; ++nj) {                                             \
                acc[mt][nj] = MFMA(AH0, asbf(bh_[nj]), acc[mt][nj]);                     \
                acc[mt][nj] = MFMA(AH1, asbf(bh_[nj] ^ SM), acc[mt][nj]);                \
            }                                                                            \
        }                                                                                \
    }

#define XPART(ts, xv0, xv1)                                                              \
    {                                                                                    \
        bf16x8 XH0 = asbf(xv0), XH1 = asbf(xv1);                                         \
        _Pragma("unroll")                                                                \
        for (int mt = 0; mt < 4; ++mt) {                                                 \
            i32x4 ah = ab[(((4 + (ts)) * 4 + mt) * 64 + lane) * 2];                      \
            bf16x8 AH = asbf(ah);                                                        \
            acc[mt][0] = MFMA(AH, XH0, acc[mt][0]);                                      \
            acc[mt][1] = MFMA(AH, XH1, acc[mt][1]);                                      \
        }                                                                                \
    }

__global__ __launch_bounds__(256, 3) void k_fuse(const ushort* __restrict__ XT,
        const ushort* __restrict__ TFB, const ushort* __restrict__ AFB,
        const float* __restrict__ bias2, float* __restrict__ out) {
    int b = blockIdx.x >> 6, lt = blockIdx.x & 63;
    int w = threadIdx.x >> 6, lane = threadIdx.x & 63;
    int col = lane & 15, kgrp = lane >> 4;
    int lbase = lt * 128 + w * 32;
    int lt0 = lbase >> 4;
    const i32x4* tb = (const i32x4*)TFB;
    const i32x4* ab = (const i32x4*)AFB + (size_t)b * 3072;
    const i32x4* xt = (const i32x4*)XT;

    f32x4 acc[4][2];
    #pragma unroll
    for (int i = 0; i < 4; ++i)
        #pragma unroll
        for (int j = 0; j < 2; ++j) acc[i][j] = (f32x4){0.f, 0.f, 0.f, 0.f};

    int sm = (col & 1) ? (int)0x80008000 : 0;
    i32x4 SM = {sm, sm, sm, sm};

    // dense x-frag loads: XT idx = ((stripe)*8192 + l)*2 + (kgrp&1), stripe = b*4+ts*2+(kgrp>>1)
    size_t xs0 = ((size_t)(b * 4 + (kgrp >> 1)) * 8192 + lbase + col) * 2 + (kgrp & 1);
    size_t xs1 = ((size_t)(b * 4 + 2 + (kgrp >> 1)) * 8192 + lbase + col) * 2 + (kgrp & 1);
    i32x4 xv00 = xt[xs0];            // ts=0, nj=0
    i32x4 xv01 = xt[xs0 + 32];       // ts=0, nj=1 (l+16 -> +32 i32x4)
    i32x4 xv10 = xt[xs1];            // ts=1, nj=0
    i32x4 xv11 = xt[xs1 + 32];       // ts=1, nj=1

    TPART(0)
    XPART(0, xv00, xv01)
    TPART(1)
    XPART(1, xv10, xv11)

    #pragma unroll
    for (int mt = 0; mt < 4; ++mt) {
        #pragma unroll
        for (int r = 0; r < 4; ++r) {
            int c = mt * 16 + kgrp * 4 + r;
            float bias = bias2[b * 64 + c];
            float* op = out + (size_t)(b * 64 + c) * L_ + lbase + col;
            #pragma unroll
            for (int nj = 0; nj < 2; ++nj) {
                float v = acc[mt][nj][r] + bias;
                op[nj * 16] = v / (1.f + __expf(-v));
            }
        }
    }
}

extern "C" void kernel_launch(void* const* d_in, const int* in_sizes, int n_in,
                              void* d_out, int out_size, void* d_ws, size_t ws_size,
                              hipStream_t stream) {
    const float* x    = (const float*)d_in[0];
    const float* emb  = (const float*)d_in[1];
    const float* wpos = (const float*)d_in[2];
    const float* wneg = (const float*)d_in[3];
    const float* Arp  = (const float*)d_in[4];
    const float* Aip  = (const float*)d_in[5];
    const float* Arn  = (const float*)d_in[6];
    const float* Ain  = (const float*)d_in[7];
    const float* w1   = (const float*)d_in[8];
    const float* b1   = (const float*)d_in[9];
    const float* w2   = (const float*)d_in[10];
    const float* b2   = (const float*)d_in[11];
    const float* lw   = (const float*)d_in[12];
    const float* lb   = (const float*)d_in[13];
    float* out = (float*)d_out;
    float* ws = (float*)d_ws;
    ushort* TFB  = (ushort*)(ws + OFF_TFB);
    ushort* TLB  = (ushort*)(ws + OFF_TLB);
    ushort* AFB  = (ushort*)(ws + OFF_AFB);
    float*  XFRP = ws + OFF_XFRP;
    float*  B2   = ws + OFF_B2;
    float*  PHI  = ws + OFF_PHI;
    float*  GB   = ws + OFF_GB;
    float*  WT   = ws + OFF_WT;
    ushort* XT   = (ushort*)(ws + OFF_XT);

    hipLaunchKernelGGL(k_init,  dim3(4272), dim3(256), 0, stream,
                       TLB, TFB, emb, Arp, Aip, Arn, Ain, PHI, w1, b1, w2, b2, GB,
                       wpos, wneg, WT);
    hipLaunchKernelGGL(k_dft,   dim3(1024), dim3(256), 0, stream, x, TLB, XFRP, XT);
    hipLaunchKernelGGL(k_mix,   dim3(288),  dim3(256), 0, stream, XFRP, WT, PHI,
                       lw, lb, GB, AFB, B2);
    hipLaunchKernelGGL(k_fuse,  dim3(2048), dim3(256), 0, stream, XT, TFB, AFB, B2, out);
}

// Round 16
// 66.427 us; speedup vs baseline: 1.0963x; 1.0162x over previous
//
#include <hip/hip_runtime.h>
#include <math.h>

#define L_ 8192
#define EMB_ 256
#define HID_ 64

typedef __attribute__((ext_vector_type(8))) short bf16x8;
typedef __attribute__((ext_vector_type(4))) float f32x4;
typedef __attribute__((ext_vector_type(4))) int i32x4;

// workspace layout (floats)
#define OFF_TFB  0           // ushort[512][2][64][8]  synthesis B-frags, hi only
#define OFF_TLB  262144      // ushort[256][4][64][8]  analysis B-frags, hi only
#define OFF_AFB  524288      // ushort[32][6][4][64][16] A-frags (hi+lo)
#define OFF_XFRP 917504      // float[8][128][2048] per-Kseg DFT partials, transposed
#define OFF_B2   3014656     // float[32*64]
#define OFF_PHI  3016704     // float[32*32*4]
#define OFF_GB   3020800     // float2[32*64]
#define OFF_WT   3024896     // float[2][32][64][64][2] transposed mix weights (2 MB)
#define OFF_XT   3549184     // dword[128][4096][16]: (bf16 x[2j,ch], bf16 x[2j+1,ch]) (33.5 MB)

__device__ inline int pkbf(float a, float b) {
    int r;
    asm volatile("v_cvt_pk_bf16_f32 %0, %1, %2" : "=v"(r) : "v"(a), "v"(b));
    return r;
}
__device__ inline bf16x8 asbf(i32x4 v) { union { i32x4 i; bf16x8 h; } u; u.i = v; return u.h; }
#define MFMA(A,B,C) __builtin_amdgcn_mfma_f32_16x16x32_bf16((A),(B),(C),0,0,0)

__device__ inline ushort f2bf(float v) {
    unsigned b = __float_as_uint(v);
    return (ushort)((b + 0x7FFFu + ((b >> 16) & 1u)) >> 16);
}
__device__ inline float bf2f(ushort h) { return __uint_as_float(((unsigned)h) << 16); }
// hardware trig: input in REVOLUTIONS; arg r/8192 is already reduced
__device__ inline float hwsin(float rev) { float r; asm("v_sin_f32 %0, %1" : "=v"(r) : "v"(rev)); return r; }
__device__ inline float hwcos(float rev) { float r; asm("v_cos_f32 %0, %1" : "=v"(r) : "v"(rev)); return r; }
// byte-select from {hi,lo}: idx 0-3 = lo bytes, 4-7 = hi bytes
__device__ inline unsigned permb(unsigned hi, unsigned lo, unsigned sel) {
    unsigned r;
    asm("v_perm_b32 %0, %1, %2, %3" : "=v"(r) : "v"(hi), "v"(lo), "v"(sel));
    return r;
}

// merged init: trig (0..4095) + phi (4096..4111) + mlp (4112..4143) + W-transpose (4144..4271)
__global__ __launch_bounds__(256) void k_init(ushort* __restrict__ TLB, ushort* __restrict__ TFB,
        const float* __restrict__ emb,
        const float* __restrict__ Arp, const float* __restrict__ Aip,
        const float* __restrict__ Arn, const float* __restrict__ Ain, float* __restrict__ phi,
        const float* __restrict__ w1, const float* __restrict__ b1,
        const float* __restrict__ w2, const float* __restrict__ b2, float* __restrict__ gb,
        const float* __restrict__ wpos, const float* __restrict__ wneg, float* __restrict__ WT) {
    int bid = blockIdx.x;
    if (bid < 4096) {
        int idx = bid * 256 + threadIdx.x;   // 0..1048575
        int f, l; ushort* dst;
        if (idx < 524288) {                  // TLB: [kstep 256][ct 4][lane 64][e 8]
            int u = idx;
            int e = u & 7, lane = (u >> 3) & 63, ct = (u >> 9) & 3, kstep = u >> 11;
            l = kstep * 32 + ((lane >> 4) << 3) + e;
            f = ct * 16 + (lane & 15);
            dst = TLB + u;
        } else {                             // TFB: [lt 512][ts 2][lane 64][e 8]
            int u = idx - 524288;
            int e = u & 7, lane = (u >> 3) & 63, ts = (u >> 9) & 1, lt = u >> 10;
            l = lt * 16 + (lane & 15);
            f = ts * 32 + ((lane >> 4) << 3) + e;
            dst = TFB + u;
        }
        int fr = f & 31; bool sinp = (f & 32) != 0;
        int r = (fr * l) & (L_ - 1);
        float rev = (float)r * (1.0f / (float)L_);
        float v = sinp ? hwsin(rev) : hwcos(rev);
        *dst = f2bf(v);
    } else if (bid < 4112) {
        int tid = (bid - 4096) * 256 + threadIdx.x;   // (b*32+mm)*4+cmp
        int b = tid >> 7;
        int mm = (tid >> 2) & 31;
        int cmp = tid & 3;
        const float* A = (cmp == 0) ? Arp : (cmp == 1) ? Aip : (cmp == 2) ? Arn : Ain;
        const float4* e4 = (const float4*)(emb + b * EMB_);
        const float4* a4 = (const float4*)(A + mm * EMB_);
        float acc = 0.f;
        for (int q = 0; q < EMB_ / 4; ++q) {
            float4 ev = e4[q], av = a4[q];
            acc += ev.x * av.x + ev.y * av.y + ev.z * av.z + ev.w * av.w;
        }
        phi[tid] = acc;
    } else if (bid < 4144) {
        __shared__ float h[HID_];
        int b = bid - 4112, t = threadIdx.x;
        if (t < HID_) {
            const float4* e4 = (const float4*)(emb + b * EMB_);
            const float4* w4 = (const float4*)(w1 + t * EMB_);
            float acc = b1[t];
            for (int q = 0; q < EMB_ / 4; ++q) {
                float4 ev = e4[q], wv = w4[q];
                acc += ev.x * wv.x + ev.y * wv.y + ev.z * wv.z + ev.w * wv.w;
            }
            h[t] = acc / (1.f + expf(-acc));
        }
        __syncthreads();
        if (t < 128) {
            float g = b2[t];
            const float4* h4 = (const float4*)h;
            const float4* w4 = (const float4*)(w2 + t * HID_);
            for (int q = 0; q < HID_ / 4; ++q) {
                float4 hv = h4[q], wv = w4[q];
                g += hv.x * wv.x + hv.y * wv.y + hv.z * wv.z + hv.w * wv.w;
            }
            if (t < 64) gb[(b * 64 + t) * 2 + 0] = 1.f + g;
            else        gb[(b * 64 + (t - 64)) * 2 + 1] = g;
        }
    } else {
        // W transpose: W[i][o][mm][ri] -> WT[side][mm][i][o][ri]
        int t = bid - 4144;              // 0..127
        int side = t >> 6, i = t & 63;
        const float* W = side ? wneg : wpos;
        const float* src = W + (size_t)i * 4096;
        int tid = threadIdx.x;
        #pragma unroll
        for (int j = 0; j < 8; ++j) {
            int u = tid + 256 * j;       // 0..2047 float2 units: mm = u>>6, o = u&63
            int mm = u >> 6, o = u & 63;
            float2 v = *(const float2*)(src + o * 64 + mm * 2);
            *(float2*)(WT + ((size_t)(side * 32 + mm)) * 8192 + i * 128 + o * 2) = v;
        }
    }
}

// single-bf16 MFMA DFT; grid 1024 = stripe(128: 16 rows) x lseg(8: K=1024); 4 waves split K
// depth-3 x prefetch + depth-2 TLB prefetch; XT2 dword-pair stores (4/iter)
__global__ __launch_bounds__(256, 4) void k_dft(const float* __restrict__ x,
        const ushort* __restrict__ TLB, float* __restrict__ xfrp, unsigned* __restrict__ XT2) {
    __shared__ float sP[4][16][132];
    int stripe = blockIdx.x >> 3;
    int lseg = blockIdx.x & 7;
    int w = threadIdx.x >> 6;
    int lane = threadIdx.x & 63;
    int row = lane & 15, koff = (lane >> 4) << 3;
    int r0 = stripe * 16;
    int kb0 = lseg * 1024 + w * 256;

    f32x4 acc[8];
    #pragma unroll
    for (int i = 0; i < 8; ++i) acc[i] = (f32x4){0.f, 0.f, 0.f, 0.f};

    const float* ap = x + (size_t)(r0 + row) * L_ + kb0 + koff;
    const i32x4* tb = (const i32x4*)TLB;
    int tbase = (kb0 >> 5) * 256 + lane;    // i32x4 index; +256 per kstep, +64 per ct
    const i32x4 SM = {(int)0x80000000, (int)0x80000000, (int)0x80000000, (int)0x80000000};
    unsigned* xtb = XT2 + ((size_t)stripe * 4096 + ((kb0 + koff) >> 1)) * 16 + row;

    float4 xa0 = *(const float4*)(ap);
    float4 xc0 = *(const float4*)(ap + 4);
    float4 xa1 = *(const float4*)(ap + 32);
    float4 xc1 = *(const float4*)(ap + 36);
    float4 xa2 = *(const float4*)(ap + 64);
    float4 xc2 = *(const float4*)(ap + 68);
    i32x4 t0 = tb[tbase], t1 = tb[tbase + 64], t2 = tb[tbase + 128], t3 = tb[tbase + 192];
    i32x4 u0 = tb[tbase + 256], u1 = tb[tbase + 320], u2 = tb[tbase + 384], u3 = tb[tbase + 448];
    #pragma unroll
    for (int ks = 0; ks < 8; ++ks) {
        float4 nxa = {0,0,0,0}, nxc = {0,0,0,0};
        i32x4 v0 = u0, v1 = u1, v2 = u2, v3 = u3;
        if (ks < 5) {
            nxa = *(const float4*)(ap + (ks + 3) * 32);
            nxc = *(const float4*)(ap + (ks + 3) * 32 + 4);
        }
        if (ks < 6) {
            int ti = tbase + (ks + 2) * 256;
            v0 = tb[ti]; v1 = tb[ti + 64]; v2 = tb[ti + 128]; v3 = tb[ti + 192];
        }
        int h0 = pkbf(xa0.x, xa0.y), h1 = pkbf(xa0.z, xa0.w);
        int h2 = pkbf(xc0.x, xc0.y), h3 = pkbf(xc0.z, xc0.w);
        bf16x8 AH = asbf((i32x4){h0, h1, h2, h3});
        acc[0] = MFMA(AH, asbf(t0), acc[0]); acc[4] = MFMA(AH, asbf(t0 ^ SM), acc[4]);
        acc[1] = MFMA(AH, asbf(t1), acc[1]); acc[5] = MFMA(AH, asbf(t1 ^ SM), acc[5]);
        acc[2] = MFMA(AH, asbf(t2), acc[2]); acc[6] = MFMA(AH, asbf(t2 ^ SM), acc[6]);
        acc[3] = MFMA(AH, asbf(t3), acc[3]); acc[7] = MFMA(AH, asbf(t3 ^ SM), acc[7]);
        // bf16 x copy, dword-pair layout: XT2[stripe][j=l/2][ch16]; 4 dword stores
        {
            unsigned* xtp = xtb + (size_t)(ks * 16) * 16;   // ks*32 l -> ks*16 j -> *16 dwords
            xtp[0]  = (unsigned)h0;
            xtp[16] = (unsigned)h1;
            xtp[32] = (unsigned)h2;
            xtp[48] = (unsigned)h3;
        }
        xa0 = xa1; xc0 = xc1; xa1 = xa2; xc1 = xc2; xa2 = nxa; xc2 = nxc;
        t0 = u0; t1 = u1; t2 = u2; t3 = u3;
        u0 = v0; u1 = v1; u2 = v2; u3 = v3;
    }
    int crow = (lane >> 4) << 2;
    int ccol = lane & 15;
    #pragma unroll
    for (int ct = 0; ct < 8; ++ct)
        #pragma unroll
        for (int r = 0; r < 4; ++r)
            sP[w][crow + r][ct * 16 + ccol] = acc[ct][r];
    __syncthreads();
    #pragma unroll
    for (int i = 0; i < 8; ++i) {
        int e = threadIdx.x + 256 * i;     // 0..2047
        int rr = e & 15, cc = e >> 4;
        float s = sP[0][rr][cc] + sP[1][rr][cc] + sP[2][rr][cc] + sP[3][rr][cc];
        xfrp[((size_t)(lseg * 128 + cc)) * 2048 + r0 + rr] = s;
    }
}

// mode mixing -> AFB fragments directly.
// blocks 0..255: [mm 32][side 2][bh 4] spectral rows (8 b each); blocks 256..287: Ax fold + bias2
__global__ __launch_bounds__(256) void k_mix(const float* __restrict__ xfrt,
        const float* __restrict__ WT,
        const float* __restrict__ phi, const float* __restrict__ lw,
        const float* __restrict__ lb, const float* __restrict__ gb,
        ushort* __restrict__ afb, float* __restrict__ bias2) {
    int bi = blockIdx.x;
    int tid = threadIdx.x;
    if (bi >= 256) {                 // Ax fold + bias2
        int b = bi - 256;
        ushort* dst = afb + (size_t)b * 24576;
        #pragma unroll
        for (int j = 0; j < 16; ++j) {
            int u = tid + 256 * j;   // 0..4095 : [ks2 2][mt 4][lane 64][e 8]
            int e = u & 7, lane = (u >> 3) & 63, mt = (u >> 9) & 3, ks2 = u >> 11;
            int c = mt * 16 + (lane & 15);
            int kk = ((lane >> 4) << 3) + e;
            float v = lw[c * 64 + ks2 * 32 + kk] * gb[(b * 64 + c) * 2];
            ushort hi = f2bf(v);
            int base = (((4 + ks2) * 4 + mt) * 64 + lane) * 16;
            dst[base + e] = hi;
            dst[base + 8 + e] = f2bf(v - bf2f(hi));
        }
        if (tid < 64) {
            float g1 = gb[(b * 64 + tid) * 2], be = gb[(b * 64 + tid) * 2 + 1];
            bias2[b * 64 + tid] = lb[tid] * g1 + be;
        }
        return;
    }
    __shared__ float sW[64][64][2];     // [i][o][re/im]
    __shared__ float sXr[8][64], sXi[8][64];   // [b_local][i]
    int bh = bi & 3, side = (bi >> 2) & 1, mm = bi >> 3;
    int slot = side ? (31 - mm) : mm;
    int colR = side ? (64 + slot) : mm;
    int colI = side ? (96 + slot) : (32 + mm);

    // stage transposed W tile: coalesced float4
    {
        const float4* wt = (const float4*)(WT + ((size_t)(side * 32 + mm)) * 8192);
        float* sWlin = &sW[0][0][0];
        #pragma unroll
        for (int j = 0; j < 8; ++j) {
            int u = tid + 256 * j;
            *(float4*)&sWlin[u * 4] = wt[u];
        }
    }
    {   // stage 8 b x 64 i sums via float2 per thread
        const float2* pR = (const float2*)(xfrt + (size_t)colR * 2048 + bh * 512);
        const float2* pI = (const float2*)(xfrt + (size_t)colI * 2048 + bh * 512);
        float2 aR = {0, 0}, aI = {0, 0};
        #pragma unroll
        for (int s = 0; s < 8; ++s) {
            float2 vR = pR[(size_t)s * 131072 + tid];
            float2 vI = pI[(size_t)s * 131072 + tid];
            aR.x += vR.x; aR.y += vR.y;
            aI.x += vI.x; aI.y += vI.y;
        }
        if (!side) { aI.x = -aI.x; aI.y = -aI.y; }
        *(float2*)&sXr[tid >> 5][(tid & 31) * 2] = aR;
        *(float2*)&sXi[tid >> 5][(tid & 31) * 2] = aI;
    }
    __syncthreads();

    int o = tid & 63, bg = tid >> 6;
    const float invL = 1.f / (float)L_;
    float fac = (slot == 0) ? invL : 2.f * invL;
    int comp = side ? 2 : 0;
    int e = slot & 7, kgrp = slot >> 3;
    int mt = o >> 4, lane = kgrp * 16 + (o & 15);
    #pragma unroll
    for (int bl = 0; bl < 2; ++bl) {
        int b_local = bg * 2 + bl;
        int b = bh * 8 + b_local;
        float sre = 0.f, sim = 0.f;
        #pragma unroll 16
        for (int i = 0; i < 64; ++i) {
            float wr = sW[i][o][0], wi = sW[i][o][1];
            float xr = sXr[b_local][i], xi = sXi[b_local][i];
            sre += xr * wr - xi * wi;
            sim += xr * wi + xi * wr;
        }
        const float* ph = &phi[(b * 32 + mm) * 4 + (side ? 2 : 0)];
        float phr = ph[0], phim = ph[1];
        float Pre = sre * phr - sim * phim;
        float Pim = sre * phim + sim * phr;
        float a = fac * Pre;
        float bcoef = (slot == 0) ? 0.f : (side ? 2.f * invL * Pim : -2.f * invL * Pim);
        ushort* dst = afb + (size_t)b * 24576;
        ushort hiA = f2bf(a);
        int baseA = ((comp * 4 + mt) * 64 + lane) * 16;
        dst[baseA + e] = hiA;
        dst[baseA + 8 + e] = f2bf(a - bf2f(hiA));
        ushort hiB = f2bf(bcoef);
        int baseB = (((comp + 1) * 4 + mt) * 64 + lane) * 16;
        dst[baseB + e] = hiB;
        dst[baseB + 8 + e] = f2bf(bcoef - bf2f(hiB));
    }
}

// MFMA epilogue GEMM: out[b][c][l] = silu( sum_k A[k][c] * B[k][l] + bias2[c] ),
// B = [T(64); (-1)^l T(64); x[b](64)]; x read from XT2 dword-pairs + v_perm parity extract.
#define TPART(ts)                                                                        \
    {                                                                                    \
        i32x4 bh_[2];                                                                    \
        _Pragma("unroll")                                                                \
        for (int nj = 0; nj < 2; ++nj)                                                   \
            bh_[nj] = tb[((lt0 + nj) * 2 + (ts)) * 64 + lane];                           \
        _Pragma("unroll")                                                                \
        for (int mt = 0; mt < 4; ++mt) {                                                 \
            i32x4 ah0 = ab[(((ts) * 4 + mt) * 64 + lane) * 2];                           \
            i32x4 ah1 = ab[(((2 + (ts)) * 4 + mt) * 64 + lane) * 2];                     \
            bf16x8 AH0 = asbf(ah0), AH1 = asbf(ah1);                                     \
            _Pragma("unroll")                                                            \
            for (int nj = 0; nj < 2; ++nj) {                                             \
                acc[mt][nj] = MFMA(AH0, asbf(bh_[nj]), acc[mt][nj]);                     \
                acc[mt][nj] = MFMA(AH1, asbf(bh_[nj] ^ SM), acc[mt][nj]);                \
            }                                                                            \
        }                                                                                \
    }

#define XPART(ts, xv0, xv1)                                                              \
    {                                                                                    \
        bf16x8 XH0 = asbf(xv0), XH1 = asbf(xv1);                                         \
        _Pragma("unroll")                                                                \
        for (int mt = 0; mt < 4; ++mt) {                                                 \
            i32x4 ah = ab[(((4 + (ts)) * 4 + mt) * 64 + lane) * 2];                      \
            bf16x8 AH = asbf(ah);                                                        \
            acc[mt][0] = MFMA(AH, XH0, acc[mt][0]);                                      \
            acc[mt][1] = MFMA(AH, XH1, acc[mt][1]);                                      \
        }                                                                                \
    }

#define XEXTRACT(q0, q1, dstvar)                                                         \
    dstvar = (i32x4){                                                                    \
        (int)permb((unsigned)q0[1], (unsigned)q0[0], sel),                               \
        (int)permb((unsigned)q0[3], (unsigned)q0[2], sel),                               \
        (int)permb((unsigned)q1[1], (unsigned)q1[0], sel),                               \
        (int)permb((unsigned)q1[3], (unsigned)q1[2], sel)};

__global__ __launch_bounds__(256, 3) void k_fuse(const unsigned* __restrict__ XT2,
        const ushort* __restrict__ TFB, const ushort* __restrict__ AFB,
        const float* __restrict__ bias2, float* __restrict__ out) {
    int b = blockIdx.x >> 6, lt = blockIdx.x & 63;
    int w = threadIdx.x >> 6, lane = threadIdx.x & 63;
    int col = lane & 15, kgrp = lane >> 4;
    int lbase = lt * 128 + w * 32;
    int lt0 = lbase >> 4;
    const i32x4* tb = (const i32x4*)TFB;
    const i32x4* ab = (const i32x4*)AFB + (size_t)b * 3072;
    const i32x4* xt4 = (const i32x4*)XT2;

    f32x4 acc[4][2];
    #pragma unroll
    for (int i = 0; i < 4; ++i)
        #pragma unroll
        for (int j = 0; j < 2; ++j) acc[i][j] = (f32x4){0.f, 0.f, 0.f, 0.f};

    int sm = (col & 1) ? (int)0x80008000 : 0;
    i32x4 SM = {sm, sm, sm, sm};
    unsigned sel = (col & 1) ? 0x07060302u : 0x05040100u;

    // XT2 i32x4 index: (stripe*4096 + j)*4 + (kgrp&1)*2, stripe = b*4 + ts*2 + (kgrp>>1)
    size_t i00 = ((size_t)(b * 4 + (kgrp >> 1)) * 4096 + ((lbase + col) >> 1)) * 4 + (kgrp & 1) * 2;
    size_t i01 = i00 + 8 * 4;           // l += 16 -> j += 8
    size_t i10 = i00 + (size_t)2 * 4096 * 4;   // ts=1 -> stripe += 2
    size_t i11 = i10 + 8 * 4;
    i32x4 q000 = xt4[i00], q001 = xt4[i00 + 1];
    i32x4 q010 = xt4[i01], q011 = xt4[i01 + 1];
    i32x4 q100 = xt4[i10], q101 = xt4[i10 + 1];
    i32x4 q110 = xt4[i11], q111 = xt4[i11 + 1];

    TPART(0)
    i32x4 xv00, xv01;
    XEXTRACT(q000, q001, xv00)
    XEXTRACT(q010, q011, xv01)
    XPART(0, xv00, xv01)
    TPART(1)
    i32x4 xv10, xv11;
    XEXTRACT(q100, q101, xv10)
    XEXTRACT(q110, q111, xv11)
    XPART(1, xv10, xv11)

    #pragma unroll
    for (int mt = 0; mt < 4; ++mt) {
        #pragma unroll
        for (int r = 0; r < 4; ++r) {
            int c = mt * 16 + kgrp * 4 + r;
            float bias = bias2[b * 64 + c];
            float* op = out + (size_t)(b * 64 + c) * L_ + lbase + col;
            #pragma unroll
            for (int nj = 0; nj < 2; ++nj) {
                float v = acc[mt][nj][r] + bias;
                op[nj * 16] = v / (1.f + __expf(-v));
            }
        }
    }
}

extern "C" void kernel_launch(void* const* d_in, const int* in_sizes, int n_in,
                              void* d_out, int out_size, void* d_ws, size_t ws_size,
                              hipStream_t stream) {
    const float* x    = (const float*)d_in[0];
    const float* emb  = (const float*)d_in[1];
    const float* wpos = (const float*)d_in[2];
    const float* wneg = (const float*)d_in[3];
    const float* Arp  = (const float*)d_in[4];
    const float* Aip  = (const float*)d_in[5];
    const float* Arn  = (const float*)d_in[6];
    const float* Ain  = (const float*)d_in[7];
    const float* w1   = (const float*)d_in[8];
    const float* b1   = (const float*)d_in[9];
    const float* w2   = (const float*)d_in[10];
    const float* b2   = (const float*)d_in[11];
    const float* lw   = (const float*)d_in[12];
    const float* lb   = (const float*)d_in[13];
    float* out = (float*)d_out;
    float* ws = (float*)d_ws;
    ushort*   TFB  = (ushort*)(ws + OFF_TFB);
    ushort*   TLB  = (ushort*)(ws + OFF_TLB);
    ushort*   AFB  = (ushort*)(ws + OFF_AFB);
    float*    XFRP = ws + OFF_XFRP;
    float*    B2   = ws + OFF_B2;
    float*    PHI  = ws + OFF_PHI;
    float*    GB   = ws + OFF_GB;
    float*    WT   = ws + OFF_WT;
    unsigned* XT2  = (unsigned*)(ws + OFF_XT);

    hipLaunchKernelGGL(k_init,  dim3(4272), dim3(256), 0, stream,
                       TLB, TFB, emb, Arp, Aip, Arn, Ain, PHI, w1, b1, w2, b2, GB,
                       wpos, wneg, WT);
    hipLaunchKernelGGL(k_dft,   dim3(1024), dim3(256), 0, stream, x, TLB, XFRP, XT2);
    hipLaunchKernelGGL(k_mix,   dim3(288),  dim3(256), 0, stream, XFRP, WT, PHI,
                       lw, lb, GB, AFB, B2);
    hipLaunchKernelGGL(k_fuse,  dim3(2048), dim3(256), 0, stream, XT2, TFB, AFB, B2, out);
}